// Round 26
// baseline (128.372 us; speedup 1.0000x reference)
//
#include <hip/hip_runtime.h>
#include <math.h>

#define T_LEN 4096
#define M_LEN 2048   // complex length after real-packing
#define V_DIM 32
#define B_DIM 128
#define NTHREADS 64           // ONE WAVE per series: zero __syncthreads
#define NSERIES 4096          // B_DIM * V_DIM
#define FS NSERIES            // feats stride: feature-major [f][sid]

// LDS bank swizzle on float2 index (r23-validated): folds addr bits 4-6 into
// 1-3 and 7-10 into 1-4. Bit 0 untouched -> b128-safe; bijective.
__device__ __forceinline__ int SW(int i) {
    return i ^ (((i >> 4) & 7) << 1) ^ (((i >> 7) & 15) << 1);
}

// storage position of frequency k after DIF [radix-4 x5, radix-2] (digit reversal)
__device__ __forceinline__ int fpos(int k) {
    return ((k & 3) << 9) | (((k >> 2) & 3) << 7) | (((k >> 4) & 3) << 5)
         | (((k >> 6) & 3) << 3) | (((k >> 8) & 3) << 1) | ((k >> 10) & 1);
}

// insert m into descending triple (a0 >= a1 >= a2)
__device__ __forceinline__ void ins3(float& a0, float& a1, float& a2, float m) {
    if (m > a0) { a2 = a1; a1 = a0; a0 = m; }
    else if (m > a1) { a2 = a1; a1 = m; }
    else if (m > a2) { a2 = m; }
}

// one radix-4 DIF butterfly at (base, quarter q) with twiddles W^j, W^2j, W^3j
__device__ __forceinline__ void bfly4(float2* Z, int base, int q,
                                      float sn, float cs, float c2, float s2,
                                      float c3, float s3) {
    const int p0 = SW(base), p1 = SW(base + q);
    const int p2i = SW(base + 2 * q), p3 = SW(base + 3 * q);
    float2 a = Z[p0], bb = Z[p1], c = Z[p2i], d = Z[p3];
    float t0r = a.x + c.x,  t0i = a.y + c.y;
    float t1r = a.x - c.x,  t1i = a.y - c.y;
    float t2r = bb.x + d.x, t2i = bb.y + d.y;
    float t3r = bb.x - d.x, t3i = bb.y - d.y;
    float y1r = t1r + t3i, y1i = t1i - t3r;
    float y2r = t0r - t2r, y2i = t0i - t2i;
    float y3r = t1r - t3i, y3i = t1i + t3r;
    Z[p0]  = make_float2(t0r + t2r, t0i + t2i);
    Z[p1]  = make_float2(y1r * cs - y1i * sn, y1r * sn + y1i * cs);
    Z[p2i] = make_float2(y2r * c2 - y2i * s2, y2r * s2 + y2i * c2);
    Z[p3]  = make_float2(y3r * c3 - y3i * s3, y3r * s3 + y3i * c3);
}

// radix-4 DIF stage (ST 0..3): 8 butterflies per lane (512 total).
// Same-wave LDS in-order execution -> no barrier between stages.
// For ST>=2, j = L & (q-1) is i-independent (64 % q == 0) -> one sincos.
template <int ST>
__device__ __forceinline__ void fft_stage_w(float2* Z, int L) {
    constexpr int lq = 9 - 2 * ST;           // log2(quarter)
    constexpr int q  = 1 << lq;
    const float scale = -3.06796158e-3f * (float)(1 << (2 * ST)); // -2pi/2048 * 4^ST
    if constexpr (ST >= 2) {
        const int j = L & (q - 1);
        float sn, cs;
        __sincosf(scale * (float)j, &sn, &cs);
        const float c2 = cs * cs - sn * sn, s2 = 2.f * cs * sn;
        const float c3 = c2 * cs - s2 * sn, s3 = c2 * sn + s2 * cs;
        #pragma unroll
        for (int i = 0; i < 8; i++) {
            const int g = (L + (i << 6)) >> lq;
            bfly4(Z, (g << (lq + 2)) + j, q, sn, cs, c2, s2, c3, s3);
        }
    } else {
        #pragma unroll
        for (int i = 0; i < 8; i++) {
            const int w = L + (i << 6);
            const int g = w >> lq;
            const int j = w & (q - 1);
            float sn, cs;
            __sincosf(scale * (float)j, &sn, &cs);
            const float c2 = cs * cs - sn * sn, s2 = 2.f * cs * sn;
            const float c3 = c2 * cs - s2 * sn, s3 = c2 * sn + s2 * cs;
            bfly4(Z, (g << (lq + 2)) + j, q, sn, cs, c2, s2, c3, s3);
        }
    }
}

// merged stage 4 (q=2; constant twiddles) + final radix-2, thread-local 8-blocks.
__device__ __forceinline__ void fft_blk8(float2* Z, int base) {
    float4 P0 = *reinterpret_cast<const float4*>(&Z[SW(base)]);      // x0,x1
    float4 P2 = *reinterpret_cast<const float4*>(&Z[SW(base + 2)]);  // x2,x3
    float4 P4 = *reinterpret_cast<const float4*>(&Z[SW(base + 4)]);  // x4,x5
    float4 P6 = *reinterpret_cast<const float4*>(&Z[SW(base + 6)]);  // x6,x7
    float t0r = P0.x + P4.x, t0i = P0.y + P4.y;
    float t1r = P0.x - P4.x, t1i = P0.y - P4.y;
    float t2r = P2.x + P6.x, t2i = P2.y + P6.y;
    float t3r = P2.x - P6.x, t3i = P2.y - P6.y;
    float o0r = t0r + t2r, o0i = t0i + t2i;
    float o2r = t1r + t3i, o2i = t1i - t3r;
    float o4r = t0r - t2r, o4i = t0i - t2i;
    float o6r = t1r - t3i, o6i = t1i + t3r;
    const float C = 0.70710678118654752f;
    float u0r = P0.z + P4.z, u0i = P0.w + P4.w;
    float u1r = P0.z - P4.z, u1i = P0.w - P4.w;
    float u2r = P2.z + P6.z, u2i = P2.w + P6.w;
    float u3r = P2.z - P6.z, u3i = P2.w - P6.w;
    float o1r = u0r + u2r, o1i = u0i + u2i;
    float y1r = u1r + u3i, y1i = u1i - u3r;
    float o3r = C * (y1r + y1i), o3i = C * (y1i - y1r);
    float y2r = u0r - u2r, y2i = u0i - u2i;
    float o5r = y2i, o5i = -y2r;
    float y3r = u1r - u3i, y3i = u1i + u3r;
    float o7r = C * (y3i - y3r), o7i = -C * (y3r + y3i);
    float4 R0 = make_float4(o0r + o1r, o0i + o1i, o0r - o1r, o0i - o1i);
    float4 R2 = make_float4(o2r + o3r, o2i + o3i, o2r - o3r, o2i - o3i);
    float4 R4 = make_float4(o4r + o5r, o4i + o5i, o4r - o5r, o4i - o5i);
    float4 R6 = make_float4(o6r + o7r, o6i + o7i, o6r - o7r, o6i - o7i);
    *reinterpret_cast<float4*>(&Z[SW(base)])     = R0;
    *reinterpret_cast<float4*>(&Z[SW(base + 2)]) = R2;
    *reinterpret_cast<float4*>(&Z[SW(base + 4)]) = R4;
    *reinterpret_cast<float4*>(&Z[SW(base + 6)]) = R6;
}

__global__ __launch_bounds__(NTHREADS, 10)   // 10 blocks/CU (LDS 10x16KB=160KB exact)
void ts_feat_kernel(const float* __restrict__ x, float* __restrict__ feats) {
    __shared__ __align__(16) float data[T_LEN];      // 16 KB swizzled packed-complex
    float2* const Z = reinterpret_cast<float2*>(&data[0]);

    const int L = threadIdx.x;             // lane 0..63 (one wave)
    // XCD swizzle: all 32 v-blocks of batch b land on XCD b&7; bijective over 4096.
    const int bid = blockIdx.x;            // 0..4095
    const int xcd = bid & 7;
    const int idx = bid >> 3;              // 0..511
    const int b   = xcd + ((idx >> 5) << 3);    // batch 0..127
    const int v   = idx & 31;
    const int sid = b * V_DIM + v;

    const float* __restrict__ px = x + (size_t)b * T_LEN * V_DIM + v;

    // ---------- load + stats: lane L owns t in [64L, 64L+64), 8 chunks of 8 ----------
    float s = 0.f, mn = 3.4e38f, mx = -3.4e38f;
    #pragma unroll
    for (int c = 0; c < 8; c++) {
        float x8[8];
        #pragma unroll
        for (int u = 0; u < 8; u++)
            x8[u] = px[(size_t)(64 * L + 8 * c + u) * V_DIM];
        #pragma unroll
        for (int u = 0; u < 8; u++) {
            s += x8[u]; mn = fminf(mn, x8[u]); mx = fmaxf(mx, x8[u]);
        }
        const int f2b = 32 * L + 4 * c;
        *reinterpret_cast<float4*>(&Z[SW(f2b)])     = make_float4(x8[0], x8[1], x8[2], x8[3]);
        *reinterpret_cast<float4*>(&Z[SW(f2b + 2)]) = make_float4(x8[4], x8[5], x8[6], x8[7]);
    }
    #pragma unroll
    for (int o = 32; o > 0; o >>= 1) {
        s += __shfl_down(s, o);
        mn = fminf(mn, __shfl_down(mn, o));
        mx = fmaxf(mx, __shfl_down(mx, o));
    }
    const float m = __shfl(s, 0) * (1.f / T_LEN);    // broadcast mean to all lanes
    __builtin_amdgcn_sched_barrier(0);

    // ---------- sweep 2: moments/slope/ACF, streaming from LDS (no barrier) ----------
    {
        float q2 = 0.f, q3 = 0.f, q4 = 0.f, qt = 0.f;
        float l1 = 0.f, l2 = 0.f, l3 = 0.f, l4 = 0.f, l5 = 0.f, l6 = 0.f;
        float p1v, p2v, p3v, p4v, p5v, p6v;
        if (L > 0) {                       // boundary x[64L-6..64L-1] (written by lane L-1)
            float2 tv = Z[SW(32 * L - 3)];
            float4 tq = *reinterpret_cast<const float4*>(&Z[SW(32 * L - 2)]);
            p6v = tv.x - m; p5v = tv.y - m;
            p4v = tq.x - m; p3v = tq.y - m; p2v = tq.z - m; p1v = tq.w - m;
        } else {
            p1v = p2v = p3v = p4v = p5v = p6v = 0.f;     // reference zero-pads
        }
        const float tf0 = (float)(L * 64) - 2047.5f;
        #pragma unroll
        for (int c = 0; c < 8; c++) {
            float4 qa = *reinterpret_cast<const float4*>(&Z[SW(32 * L + 4 * c)]);
            float4 qb = *reinterpret_cast<const float4*>(&Z[SW(32 * L + 4 * c + 2)]);
            float x8[8] = {qa.x, qa.y, qa.z, qa.w, qb.x, qb.y, qb.z, qb.w};
            #pragma unroll
            for (int u = 0; u < 8; u++) {
                float cv = x8[u] - m;
                float cc = cv * cv;
                q2 += cc; q3 += cc * cv; q4 += cc * cc;
                qt += cv * (tf0 + (float)(8 * c + u));
                l1 += p1v * cv; l2 += p2v * cv; l3 += p3v * cv;
                l4 += p4v * cv; l5 += p5v * cv; l6 += p6v * cv;
                p6v = p5v; p5v = p4v; p4v = p3v; p3v = p2v; p2v = p1v; p1v = cv;
            }
        }
        #pragma unroll
        for (int o = 32; o > 0; o >>= 1) {
            q2 += __shfl_down(q2, o); q3 += __shfl_down(q3, o);
            q4 += __shfl_down(q4, o); qt += __shfl_down(qt, o);
            l1 += __shfl_down(l1, o); l2 += __shfl_down(l2, o);
            l3 += __shfl_down(l3, o); l4 += __shfl_down(l4, o);
            l5 += __shfl_down(l5, o); l6 += __shfl_down(l6, o);
        }
        if (L == 0) {                      // lane 0 holds all totals + mn/mx
            float c2t = q2, c3t = q3, c4t = q4, ct = qt;
            float var = c2t * (1.f / T_LEN);
            float sd  = sqrtf(var + 1e-8f);
            float i3  = 1.f / (sd * sd * sd);
            float dn  = c2t + 1e-8f;
            float* fp = feats + sid;
            fp[0 * FS] = m; fp[1 * FS] = sd;
            fp[2 * FS] = c3t * (1.f / T_LEN) * i3;
            fp[3 * FS] = c4t * (1.f / T_LEN) * i3 / sd;
            fp[4 * FS] = mn; fp[5 * FS] = mx;
            fp[6 * FS] = ct / 5726622720.f;              // sum(tc^2) = T(T^2-1)/12
            fp[10 * FS] = l1 / dn; fp[11 * FS] = l2 / dn; fp[12 * FS] = l3 / dn;
            fp[13 * FS] = l4 / dn; fp[14 * FS] = l5 / dn; fp[15 * FS] = l6 / dn;
        }
    }
    __builtin_amdgcn_sched_barrier(0);

    // ---------- FFT: 4 radix-4 stages + merged stage4/radix-2, barrier-free ----------
    fft_stage_w<0>(Z, L);  __builtin_amdgcn_sched_barrier(0);
    fft_stage_w<1>(Z, L);  __builtin_amdgcn_sched_barrier(0);
    fft_stage_w<2>(Z, L);  __builtin_amdgcn_sched_barrier(0);
    fft_stage_w<3>(Z, L);  __builtin_amdgcn_sched_barrier(0);
    #pragma unroll
    for (int i = 0; i < 4; i++) {
        fft_blk8(Z, (L + (i << 6)) * 8);   // thread-local 8-point blocks
    }
    __builtin_amdgcn_sched_barrier(0);

    // ---------- magnitudes: conjugate pair once; mag^2, sqrt deferred ----------
    // X_k = (Er+u, Ei+v), X_{2048-k} = (Er-u, v-Ei); radix-2 already applied.
    const float inv_T = 1.f / (float)T_LEN;
    float a0 = -1.f, a1 = -1.f, a2 = -1.f;               // top-3 of |X|^2
    #pragma unroll
    for (int i = 0; i < 16; i++) {
        int k  = 1 + L + (i << 6);                       // 1..1024 bijectively
        int pa = fpos(k);
        int pb = fpos(M_LEN - k);
        float ang = (float)k * (-3.14159265358979f / (float)M_LEN);
        float sn, cs; __sincosf(ang, &sn, &cs);
        float2 Za = Z[SW(pa)], Zb = Z[SW(pb)];
        float Er = 0.5f * (Za.x + Zb.x), Ei = 0.5f * (Za.y - Zb.y);
        float Or = 0.5f * (Za.y + Zb.y), Oi = 0.5f * (Zb.x - Za.x);
        float u = cs * Or - sn * Oi, vv = cs * Oi + sn * Or;
        float Xr = Er + u, Xi = Ei + vv;
        ins3(a0, a1, a2, Xr * Xr + Xi * Xi);
        if (k != 1024) {
            float Yr = Er - u, Yi = vv - Ei;
            ins3(a0, a1, a2, Yr * Yr + Yi * Yi);
        }
    }
    if (L == 0) {                                        // Nyquist k=2048
        float2 Z0 = Z[SW(0)];
        float d = Z0.x - Z0.y;
        ins3(a0, a1, a2, d * d);
    }
    #pragma unroll
    for (int o = 32; o > 0; o >>= 1) {
        float u0 = __shfl_down(a0, o), u1 = __shfl_down(a1, o), u2 = __shfl_down(a2, o);
        ins3(a0, a1, a2, u0); ins3(a0, a1, a2, u1); ins3(a0, a1, a2, u2);
    }
    if (L == 0) {
        float* fp = feats + sid;
        fp[7 * FS] = sqrtf(a0) * inv_T;
        fp[8 * FS] = sqrtf(a1) * inv_T;
        fp[9 * FS] = sqrtf(a2) * inv_T;
    }
}

// One 32-lane group per (b, f): coalesced 128-B read + shuffle reduce.
__global__ __launch_bounds__(256)
void ts_reduce_kernel(const float* __restrict__ feats, float* __restrict__ out) {
    const int tid = threadIdx.x;
    const int lane = tid & 63;
    const int wid = blockIdx.x * 4 + (tid >> 6);      // global wave 0..1023
    const int pairidx = wid * 2 + (lane >> 5);        // (b,f) pair 0..2047
    const int b = pairidx >> 4, f = pairidx & 15;
    const int v = lane & 31;
    float val = feats[f * FS + b * V_DIM + v];
    float s = val;
    #pragma unroll
    for (int o = 16; o > 0; o >>= 1) s += __shfl_xor(s, o);
    float m = s * (1.f / V_DIM);
    float d = val - m;
    float q = d * d;
    #pragma unroll
    for (int o = 16; o > 0; o >>= 1) q += __shfl_xor(q, o);
    float sd = sqrtf(q * (1.f / V_DIM));
    if (v == 0) {
        out[b * 32 + f]      = fminf(fmaxf(m,  -5.f), 5.f);
        out[b * 32 + 16 + f] = fminf(fmaxf(sd, -5.f), 5.f);
    }
}

extern "C" void kernel_launch(void* const* d_in, const int* in_sizes, int n_in,
                              void* d_out, int out_size, void* d_ws, size_t ws_size,
                              hipStream_t stream) {
    const float* x = (const float*)d_in[0];
    float* out = (float*)d_out;
    float* feats = (float*)d_ws;   // feature-major [16][4096] = 256 KB

    hipLaunchKernelGGL(ts_feat_kernel, dim3(NSERIES), dim3(NTHREADS), 0, stream,
                       x, feats);
    hipLaunchKernelGGL(ts_reduce_kernel, dim3(256), dim3(256), 0, stream,
                       feats, out);
}